// Round 1
// baseline (1635.023 us; speedup 1.0000x reference)
//
#include <hip/hip_runtime.h>
#include <cstdint>

// ---- PRNG mode: 1 = jax_threefry_partitionable (default since JAX 0.4.36),
//                 0 = legacy "original" threefry counter layout.
#define PARTITIONABLE 1

static constexpr int Bsz = 4, Lsz = 1024, Dsz = 1024, Hn = 16, HDsz = 64;
static constexpr size_t ELEMS = (size_t)Bsz * Lsz * Dsz;     // 4194304
static constexpr uint32_t HALF_N = (uint32_t)(ELEMS / 2);    // 2097152
static constexpr float SCALE = 0.125f;                        // 1/sqrt(64)
static constexpr float P_NOISE = 0.05f;
static constexpr float S_NOISE = 0.1f;

// ---------------- threefry2x32 (exact JAX semantics) ----------------
__host__ __device__ __forceinline__ void tf2x32(uint32_t k0, uint32_t k1,
                                                uint32_t x0, uint32_t x1,
                                                uint32_t& o0, uint32_t& o1) {
  uint32_t ks2 = k0 ^ k1 ^ 0x1BD11BDAu;
  x0 += k0; x1 += k1;
#define TFR(r) { x0 += x1; x1 = (x1 << (r)) | (x1 >> (32 - (r))); x1 ^= x0; }
  TFR(13) TFR(15) TFR(26) TFR(6)
  x0 += k1; x1 += ks2 + 1u;
  TFR(17) TFR(29) TFR(16) TFR(24)
  x0 += ks2; x1 += k0 + 2u;
  TFR(13) TFR(15) TFR(26) TFR(6)
  x0 += k0; x1 += k1 + 3u;
  TFR(17) TFR(29) TFR(16) TFR(24)
  x0 += k1; x1 += ks2 + 4u;
  TFR(13) TFR(15) TFR(26) TFR(6)
  x0 += ks2; x1 += k0 + 5u;
#undef TFR
  o0 = x0; o1 = x1;
}

struct KeySet { uint32_t k[5][2]; };     // phase, amp, nr, ni, meas
struct AllKeys { KeySet t[3]; };         // q, k, v

__device__ __forceinline__ uint32_t draw_bits(uint32_t k0, uint32_t k1, uint32_t idx) {
#if PARTITIONABLE
  uint32_t o0, o1; tf2x32(k0, k1, 0u, idx, o0, o1);
  return o0 ^ o1;
#else
  uint32_t o0, o1;
  if (idx < HALF_N) { tf2x32(k0, k1, idx, idx + HALF_N, o0, o1); return o0; }
  tf2x32(k0, k1, idx - HALF_N, idx, o0, o1); return o1;
#endif
}

__device__ __forceinline__ float unif01(uint32_t bits) {
  return __uint_as_float((bits >> 9) | 0x3f800000u) - 1.0f;
}

// sqrt(2) * erfinv(uniform(lo=nextafter(-1,0), hi=1))  -- XLA ErfInv32 polynomial
__device__ __forceinline__ float normal_from_bits(uint32_t bits) {
  const float LO = -0.99999994f;   // 0xBF7FFFFF
  float f = unif01(bits);
  float x = fmaxf(LO, f * 2.0f + LO);   // f*2 exact -> bit-exact vs XLA
  float w = -log1pf(-x * x);
  float p;
  if (w < 5.0f) {
    w = w - 2.5f;
    p = 2.81022636e-08f;
    p = fmaf(p, w, 3.43273939e-07f);
    p = fmaf(p, w, -3.5233877e-06f);
    p = fmaf(p, w, -4.39150654e-06f);
    p = fmaf(p, w, 0.00021858087f);
    p = fmaf(p, w, -0.00125372503f);
    p = fmaf(p, w, -0.00417768164f);
    p = fmaf(p, w, 0.246640727f);
    p = fmaf(p, w, 1.50140941f);
  } else {
    w = sqrtf(w) - 3.0f;
    p = -0.000200214257f;
    p = fmaf(p, w, 0.000100950558f);
    p = fmaf(p, w, 0.00134934322f);
    p = fmaf(p, w, -0.00367342844f);
    p = fmaf(p, w, 0.00573950773f);
    p = fmaf(p, w, -0.0076224613f);
    p = fmaf(p, w, 0.00943887047f);
    p = fmaf(p, w, 1.00167406f);
    p = fmaf(p, w, 2.83297682f);
  }
  return 1.41421356f * (p * x);
}

// ---------------- GEMM: Y[m,n] = sum_k X[m,k]*W[n,k] + bias[n]  (M=4096,N=K=1024)
struct GemmBatch { const float* X[6]; const float* W[6]; const float* Bv[6]; float* Y[6]; };

__global__ __launch_bounds__(256) void gemm_nt_kernel(GemmBatch jobs) {
  const int jz = blockIdx.z;
  const float* __restrict__ X = jobs.X[jz];
  const float* __restrict__ W = jobs.W[jz];
  const float* __restrict__ bias = jobs.Bv[jz];
  float* __restrict__ Y = jobs.Y[jz];
  const int n0 = blockIdx.x * 64, m0 = blockIdx.y * 64;
  __shared__ float Xs[16][68];
  __shared__ float Ws[16][68];
  const int tid = (int)threadIdx.x;
  const int tx = tid & 15, ty = tid >> 4;
  const int lrow = tid >> 2, lc4 = (tid & 3) * 4;
  float acc[4][4] = {};
  const float* xp = X + (size_t)(m0 + lrow) * Dsz + lc4;
  const float* wp = W + (size_t)(n0 + lrow) * Dsz + lc4;
  for (int k0 = 0; k0 < Dsz; k0 += 16) {
    float4 xv = *(const float4*)(xp + k0);
    float4 wv = *(const float4*)(wp + k0);
    __syncthreads();
    Xs[lc4 + 0][lrow] = xv.x; Xs[lc4 + 1][lrow] = xv.y;
    Xs[lc4 + 2][lrow] = xv.z; Xs[lc4 + 3][lrow] = xv.w;
    Ws[lc4 + 0][lrow] = wv.x; Ws[lc4 + 1][lrow] = wv.y;
    Ws[lc4 + 2][lrow] = wv.z; Ws[lc4 + 3][lrow] = wv.w;
    __syncthreads();
#pragma unroll
    for (int kk = 0; kk < 16; ++kk) {
      float a[4], bb[4];
#pragma unroll
      for (int i = 0; i < 4; ++i) a[i] = Xs[kk][ty * 4 + i];
#pragma unroll
      for (int j = 0; j < 4; ++j) bb[j] = Ws[kk][tx * 4 + j];
#pragma unroll
      for (int i = 0; i < 4; ++i)
#pragma unroll
        for (int j = 0; j < 4; ++j) acc[i][j] = fmaf(a[i], bb[j], acc[i][j]);
    }
  }
  float bv[4];
#pragma unroll
  for (int j = 0; j < 4; ++j) bv[j] = bias[n0 + tx * 4 + j];
#pragma unroll
  for (int i = 0; i < 4; ++i) {
    float4 o = make_float4(acc[i][0] + bv[0], acc[i][1] + bv[1],
                           acc[i][2] + bv[2], acc[i][3] + bv[3]);
    *(float4*)&Y[(size_t)(m0 + ty * 4 + i) * Dsz + n0 + tx * 4] = o;
  }
}

// ---------------- noise + diag(ent) scaling, in place on q/k/v ----------------
__global__ __launch_bounds__(256) void noise_kernel(
    float* __restrict__ qr, float* __restrict__ qi,
    float* __restrict__ kr, float* __restrict__ ki,
    float* __restrict__ vr, float* __restrict__ vi,
    const float* __restrict__ ent, AllKeys keys) {
  const uint32_t e = blockIdx.x * 256u + threadIdx.x;
  const int j = (int)blockIdx.y;
  float* re; float* im;
  if (j == 0) { re = qr; im = qi; } else if (j == 1) { re = kr; im = ki; }
  else { re = vr; im = vi; }
  const KeySet& ks = keys.t[j];
  const uint32_t b_phase = draw_bits(ks.k[0][0], ks.k[0][1], e);
  const uint32_t b_amp   = draw_bits(ks.k[1][0], ks.k[1][1], e);
  const uint32_t b_nr    = draw_bits(ks.k[2][0], ks.k[2][1], e);
  const uint32_t b_ni    = draw_bits(ks.k[3][0], ks.k[3][1], e);
  const uint32_t b_meas  = draw_bits(ks.k[4][0], ks.k[4][1], e);
  const float flip = (unif01(b_phase) < P_NOISE) ? -1.0f : 1.0f;
  const float amp  = (unif01(b_amp)  < P_NOISE) ? 1.0f : 0.0f;
  const float keep = (unif01(b_meas) < P_NOISE * 0.5f) ? 0.0f : 1.0f;
  const float nr = normal_from_bits(b_nr);
  const float ni = normal_from_bits(b_ni);
  float r  = re[e], iv = im[e];
  r  = (r  * flip + nr * S_NOISE * amp) * keep;
  iv = (iv * flip + ni * S_NOISE * amp) * keep;
  if (j != 2) {  // per-head diag(ent) scaling applies to q and k only
    const int h = ((int)e & (Dsz - 1)) >> 6;
    const float d = ent[h * Hn + h];
    r *= d; iv *= d;
  }
  re[e] = r; im[e] = iv;
}

// ---------------- scores: raw S[b,h,q,k] = SCALE*(qr.kr + qi.ki), masked ------
__global__ __launch_bounds__(256) void scores_kernel(
    const float* __restrict__ qr, const float* __restrict__ qi,
    const float* __restrict__ kr, const float* __restrict__ ki,
    const int* __restrict__ mask, float* __restrict__ attn) {
  const int bh = (int)blockIdx.z;
  const int b = bh >> 4, h = bh & 15;
  const size_t base = (size_t)b * Lsz * Dsz + (size_t)h * HDsz;
  const int k0c = blockIdx.x * 64, q0 = blockIdx.y * 64;
  __shared__ float Qs[16][68];
  __shared__ float Ks[16][68];
  const int tid = (int)threadIdx.x;
  const int tx = tid & 15, ty = tid >> 4;
  const int lrow = tid >> 2, lc4 = (tid & 3) * 4;
  float acc[4][4] = {};
  for (int c = 0; c < 8; ++c) {
    const float* Qb = (c < 4) ? qr : qi;
    const float* Kb = (c < 4) ? kr : ki;
    const int d0 = (c & 3) * 16;
    float4 xv = *(const float4*)&Qb[base + (size_t)(q0 + lrow) * Dsz + d0 + lc4];
    float4 wv = *(const float4*)&Kb[base + (size_t)(k0c + lrow) * Dsz + d0 + lc4];
    __syncthreads();
    Qs[lc4 + 0][lrow] = xv.x; Qs[lc4 + 1][lrow] = xv.y;
    Qs[lc4 + 2][lrow] = xv.z; Qs[lc4 + 3][lrow] = xv.w;
    Ks[lc4 + 0][lrow] = wv.x; Ks[lc4 + 1][lrow] = wv.y;
    Ks[lc4 + 2][lrow] = wv.z; Ks[lc4 + 3][lrow] = wv.w;
    __syncthreads();
#pragma unroll
    for (int kk = 0; kk < 16; ++kk) {
      float a[4], bb[4];
#pragma unroll
      for (int i = 0; i < 4; ++i) a[i] = Qs[kk][ty * 4 + i];
#pragma unroll
      for (int j = 0; j < 4; ++j) bb[j] = Ks[kk][tx * 4 + j];
#pragma unroll
      for (int i = 0; i < 4; ++i)
#pragma unroll
        for (int j = 0; j < 4; ++j) acc[i][j] = fmaf(a[i], bb[j], acc[i][j]);
    }
  }
  const int kc = k0c + tx * 4;
  int mk[4];
#pragma unroll
  for (int j = 0; j < 4; ++j) mk[j] = mask[b * Lsz + kc + j];
#pragma unroll
  for (int i = 0; i < 4; ++i) {
    float4 o;
    o.x = (mk[0] == 0) ? -1e9f : acc[i][0] * SCALE;
    o.y = (mk[1] == 0) ? -1e9f : acc[i][1] * SCALE;
    o.z = (mk[2] == 0) ? -1e9f : acc[i][2] * SCALE;
    o.w = (mk[3] == 0) ? -1e9f : acc[i][3] * SCALE;
    *(float4*)&attn[((size_t)bh * Lsz + (q0 + ty * 4 + i)) * Lsz + kc] = o;
  }
}

// ---------------- softmax in place over last dim (rows of 1024) ----------------
__global__ __launch_bounds__(256) void softmax_kernel(float* __restrict__ attn) {
  const size_t row = blockIdx.x;
  float* p = attn + row * (size_t)Lsz;
  const int t = (int)threadIdx.x;
  float4 v = ((float4*)p)[t];
  float m = fmaxf(fmaxf(v.x, v.y), fmaxf(v.z, v.w));
  __shared__ float red[4];
  const int lane = t & 63, wv = t >> 6;
#pragma unroll
  for (int off = 32; off; off >>= 1) m = fmaxf(m, __shfl_down(m, off));
  if (lane == 0) red[wv] = m;
  __syncthreads();
  m = fmaxf(fmaxf(red[0], red[1]), fmaxf(red[2], red[3]));
  float e0 = expf(v.x - m), e1 = expf(v.y - m), e2 = expf(v.z - m), e3 = expf(v.w - m);
  float s = (e0 + e1) + (e2 + e3);
  __syncthreads();
#pragma unroll
  for (int off = 32; off; off >>= 1) s += __shfl_down(s, off);
  if (lane == 0) red[wv] = s;
  __syncthreads();
  s = (red[0] + red[1]) + (red[2] + red[3]);
  ((float4*)p)[t] = make_float4(e0 / s, e1 / s, e2 / s, e3 / s);
}

// ---------------- PV: out[b,q,h*64+d] = sum_k attn[b,h,q,k] * v[b,k,h*64+d] ----
__global__ __launch_bounds__(256) void pv_kernel(
    const float* __restrict__ attn, const float* __restrict__ vr,
    const float* __restrict__ vi, float* __restrict__ or_, float* __restrict__ oi_) {
  const int bh = (int)blockIdx.y;
  const int b = bh >> 4, h = bh & 15;
  const int q0 = blockIdx.x * 64;
  const float* arow = attn + (size_t)bh * Lsz * Lsz;
  const size_t vbase = (size_t)b * Lsz * Dsz + (size_t)h * HDsz;
  __shared__ float As[32][68];
  __shared__ float Vr[32][68];
  __shared__ float Vi[32][68];
  const int tid = (int)threadIdx.x;
  const int tx = tid & 15, ty = tid >> 4;
  const int r1 = tid >> 2, c1 = (tid & 3) * 4;
  const int r2 = tid >> 3, c2 = (tid & 7) * 8;
  float ar[4][4] = {}, ai[4][4] = {};
  for (int k0 = 0; k0 < Lsz; k0 += 32) {
    float4 a0 = *(const float4*)&arow[(size_t)(q0 + r1) * Lsz + k0 + c1];
    float4 a1 = *(const float4*)&arow[(size_t)(q0 + r1) * Lsz + k0 + 16 + c1];
    float4 v0 = *(const float4*)&vr[vbase + (size_t)(k0 + r2) * Dsz + c2];
    float4 v1 = *(const float4*)&vr[vbase + (size_t)(k0 + r2) * Dsz + c2 + 4];
    float4 w0 = *(const float4*)&vi[vbase + (size_t)(k0 + r2) * Dsz + c2];
    float4 w1 = *(const float4*)&vi[vbase + (size_t)(k0 + r2) * Dsz + c2 + 4];
    __syncthreads();
    As[c1 + 0][r1] = a0.x; As[c1 + 1][r1] = a0.y;
    As[c1 + 2][r1] = a0.z; As[c1 + 3][r1] = a0.w;
    As[16 + c1 + 0][r1] = a1.x; As[16 + c1 + 1][r1] = a1.y;
    As[16 + c1 + 2][r1] = a1.z; As[16 + c1 + 3][r1] = a1.w;
    *(float4*)&Vr[r2][c2] = v0; *(float4*)&Vr[r2][c2 + 4] = v1;
    *(float4*)&Vi[r2][c2] = w0; *(float4*)&Vi[r2][c2 + 4] = w1;
    __syncthreads();
#pragma unroll
    for (int kk = 0; kk < 32; ++kk) {
      float a[4], br[4], bi[4];
#pragma unroll
      for (int i = 0; i < 4; ++i) a[i] = As[kk][ty * 4 + i];
#pragma unroll
      for (int j = 0; j < 4; ++j) { br[j] = Vr[kk][tx * 4 + j]; bi[j] = Vi[kk][tx * 4 + j]; }
#pragma unroll
      for (int i = 0; i < 4; ++i)
#pragma unroll
        for (int j = 0; j < 4; ++j) {
          ar[i][j] = fmaf(a[i], br[j], ar[i][j]);
          ai[i][j] = fmaf(a[i], bi[j], ai[i][j]);
        }
    }
  }
#pragma unroll
  for (int i = 0; i < 4; ++i) {
    const size_t orow = (size_t)(b * Lsz + q0 + ty * 4 + i) * Dsz + h * HDsz + tx * 4;
    *(float4*)&or_[orow] = make_float4(ar[i][0], ar[i][1], ar[i][2], ar[i][3]);
    *(float4*)&oi_[orow] = make_float4(ai[i][0], ai[i][1], ai[i][2], ai[i][3]);
  }
}

extern "C" void kernel_launch(void* const* d_in, const int* in_sizes, int n_in,
                              void* d_out, int out_size, void* d_ws, size_t ws_size,
                              hipStream_t stream) {
  const float* x_real = (const float*)d_in[0];
  const float* x_imag = (const float*)d_in[1];
  const int*   mask   = (const int*)d_in[2];
  const float* qr_w = (const float*)d_in[3];  const float* qr_b = (const float*)d_in[4];
  const float* qi_w = (const float*)d_in[5];  const float* qi_b = (const float*)d_in[6];
  const float* kr_w = (const float*)d_in[7];  const float* kr_b = (const float*)d_in[8];
  const float* ki_w = (const float*)d_in[9];  const float* ki_b = (const float*)d_in[10];
  const float* vr_w = (const float*)d_in[11]; const float* vr_b = (const float*)d_in[12];
  const float* vi_w = (const float*)d_in[13]; const float* vi_b = (const float*)d_in[14];
  const float* or_w = (const float*)d_in[15]; const float* or_b = (const float*)d_in[16];
  const float* oi_w = (const float*)d_in[17]; const float* oi_b = (const float*)d_in[18];
  const float* ent  = (const float*)d_in[19];

  float* out_real = (float*)d_out;
  float* out_imag = out_real + ELEMS;
  float* attn     = out_imag + ELEMS;            // [B,H,L,L] = 64M floats

  if (ws_size < 6 * ELEMS * sizeof(float)) return;  // need 96 MB scratch
  float* ws = (float*)d_ws;
  float* qr = ws + 0 * ELEMS; float* qi = ws + 1 * ELEMS;
  float* kr = ws + 2 * ELEMS; float* ki = ws + 3 * ELEMS;
  float* vr = ws + 4 * ELEMS; float* vi = ws + 5 * ELEMS;
  float* or_tmp = qr;  // qr/qi dead after scores; reuse for attention output
  float* oi_tmp = qi;

  // ---- host-side key derivation: nkey = key(1) = (0,1)
  AllKeys keys;
  for (int j = 0; j < 3; ++j) {
    uint32_t a, b2;
    tf2x32(0u, 1u, 0u, (uint32_t)j, a, b2);          // fold_in(nkey, j)
#if PARTITIONABLE
    for (int i = 0; i < 5; ++i)
      tf2x32(a, b2, 0u, (uint32_t)i, keys.t[j].k[i][0], keys.t[j].k[i][1]);
#else
    uint32_t out10[10];
    for (int i = 0; i < 5; ++i) {
      uint32_t o0, o1; tf2x32(a, b2, (uint32_t)i, (uint32_t)(i + 5), o0, o1);
      out10[i] = o0; out10[i + 5] = o1;
    }
    for (int i = 0; i < 5; ++i) { keys.t[j].k[i][0] = out10[2*i]; keys.t[j].k[i][1] = out10[2*i+1]; }
#endif
  }

  // 1) six projection GEMMs
  GemmBatch pj;
  const float* xs[6] = {x_real, x_imag, x_real, x_imag, x_real, x_imag};
  const float* wsp[6] = {qr_w, qi_w, kr_w, ki_w, vr_w, vi_w};
  const float* bsp[6] = {qr_b, qi_b, kr_b, ki_b, vr_b, vi_b};
  float* ysp[6] = {qr, qi, kr, ki, vr, vi};
  for (int i = 0; i < 6; ++i) { pj.X[i] = xs[i]; pj.W[i] = wsp[i]; pj.Bv[i] = bsp[i]; pj.Y[i] = ysp[i]; }
  gemm_nt_kernel<<<dim3(16, 64, 6), 256, 0, stream>>>(pj);

  // 2) quantum noise + diag(ent) scaling (in place)
  noise_kernel<<<dim3((uint32_t)(ELEMS / 256), 3), 256, 0, stream>>>(qr, qi, kr, ki, vr, vi, ent, keys);

  // 3) raw interference scores into attn region
  scores_kernel<<<dim3(16, 16, 64), 256, 0, stream>>>(qr, qi, kr, ki, mask, attn);

  // 4) softmax in place (attn is a required output)
  softmax_kernel<<<dim3(Bsz * Hn * Lsz), 256, 0, stream>>>(attn);

  // 5) PV for real and imag
  pv_kernel<<<dim3(16, 64), 256, 0, stream>>>(attn, vr, vi, or_tmp, oi_tmp);

  // 6) output projections
  GemmBatch oj;
  for (int i = 0; i < 6; ++i) { oj.X[i] = nullptr; oj.W[i] = nullptr; oj.Bv[i] = nullptr; oj.Y[i] = nullptr; }
  oj.X[0] = or_tmp; oj.W[0] = or_w; oj.Bv[0] = or_b; oj.Y[0] = out_real;
  oj.X[1] = oi_tmp; oj.W[1] = oi_w; oj.Bv[1] = oi_b; oj.Y[1] = out_imag;
  gemm_nt_kernel<<<dim3(16, 64, 2), 256, 0, stream>>>(oj);
}

// Round 2
// 1016.114 us; speedup vs baseline: 1.6091x; 1.6091x over previous
//
#include <hip/hip_runtime.h>
#include <cstdint>

#define PARTITIONABLE 1

static constexpr int Bsz = 4, Lsz = 1024, Dsz = 1024, Hn = 16, HDsz = 64;
static constexpr size_t ELEMS = (size_t)Bsz * Lsz * Dsz;     // 4194304
static constexpr uint32_t HALF_N = (uint32_t)(ELEMS / 2);
static constexpr float SCALE = 0.125f;
static constexpr float P_NOISE = 0.05f;
static constexpr float S_NOISE = 0.1f;

typedef __attribute__((ext_vector_type(8))) short short8v;   // 8 bf16 (4 VGPR)
typedef __attribute__((ext_vector_type(4))) float floatx4;   // MFMA acc

// ---------------- threefry2x32 (exact JAX semantics) ----------------
__host__ __device__ __forceinline__ void tf2x32(uint32_t k0, uint32_t k1,
                                                uint32_t x0, uint32_t x1,
                                                uint32_t& o0, uint32_t& o1) {
  uint32_t ks2 = k0 ^ k1 ^ 0x1BD11BDAu;
  x0 += k0; x1 += k1;
#define TFR(r) { x0 += x1; x1 = (x1 << (r)) | (x1 >> (32 - (r))); x1 ^= x0; }
  TFR(13) TFR(15) TFR(26) TFR(6)
  x0 += k1; x1 += ks2 + 1u;
  TFR(17) TFR(29) TFR(16) TFR(24)
  x0 += ks2; x1 += k0 + 2u;
  TFR(13) TFR(15) TFR(26) TFR(6)
  x0 += k0; x1 += k1 + 3u;
  TFR(17) TFR(29) TFR(16) TFR(24)
  x0 += k1; x1 += ks2 + 4u;
  TFR(13) TFR(15) TFR(26) TFR(6)
  x0 += ks2; x1 += k0 + 5u;
#undef TFR
  o0 = x0; o1 = x1;
}

struct KeySet { uint32_t k[5][2]; };
struct AllKeys { KeySet t[3]; };

__device__ __forceinline__ uint32_t draw_bits(uint32_t k0, uint32_t k1, uint32_t idx) {
#if PARTITIONABLE
  uint32_t o0, o1; tf2x32(k0, k1, 0u, idx, o0, o1);
  return o0 ^ o1;
#else
  uint32_t o0, o1;
  if (idx < HALF_N) { tf2x32(k0, k1, idx, idx + HALF_N, o0, o1); return o0; }
  tf2x32(k0, k1, idx - HALF_N, idx, o0, o1); return o1;
#endif
}

__device__ __forceinline__ float unif01(uint32_t bits) {
  return __uint_as_float((bits >> 9) | 0x3f800000u) - 1.0f;
}

__device__ __forceinline__ float normal_from_bits(uint32_t bits) {
  const float LO = -0.99999994f;
  float f = unif01(bits);
  float x = fmaxf(LO, f * 2.0f + LO);
  float w = -log1pf(-x * x);
  float p;
  if (w < 5.0f) {
    w = w - 2.5f;
    p = 2.81022636e-08f;
    p = fmaf(p, w, 3.43273939e-07f);
    p = fmaf(p, w, -3.5233877e-06f);
    p = fmaf(p, w, -4.39150654e-06f);
    p = fmaf(p, w, 0.00021858087f);
    p = fmaf(p, w, -0.00125372503f);
    p = fmaf(p, w, -0.00417768164f);
    p = fmaf(p, w, 0.246640727f);
    p = fmaf(p, w, 1.50140941f);
  } else {
    w = sqrtf(w) - 3.0f;
    p = -0.000200214257f;
    p = fmaf(p, w, 0.000100950558f);
    p = fmaf(p, w, 0.00134934322f);
    p = fmaf(p, w, -0.00367342844f);
    p = fmaf(p, w, 0.00573950773f);
    p = fmaf(p, w, -0.0076224613f);
    p = fmaf(p, w, 0.00943887047f);
    p = fmaf(p, w, 1.00167406f);
    p = fmaf(p, w, 2.83297682f);
  }
  return 1.41421356f * (p * x);
}

// ---------------- f32 -> (hi,lo) bf16 split ----------------
__device__ __forceinline__ uint32_t bf16_rn(float f) {
  uint32_t u = __float_as_uint(f);
  return (u + 0x7FFFu + ((u >> 16) & 1u)) >> 16;
}
__device__ __forceinline__ void cvt_split(float4 v, uint64_t& hi, uint64_t& lo) {
  uint32_t h0 = bf16_rn(v.x), h1 = bf16_rn(v.y), h2 = bf16_rn(v.z), h3 = bf16_rn(v.w);
  float r0 = v.x - __uint_as_float(h0 << 16);
  float r1 = v.y - __uint_as_float(h1 << 16);
  float r2 = v.z - __uint_as_float(h2 << 16);
  float r3 = v.w - __uint_as_float(h3 << 16);
  uint32_t l0 = bf16_rn(r0), l1 = bf16_rn(r1), l2 = bf16_rn(r2), l3 = bf16_rn(r3);
  hi = (uint64_t)h0 | ((uint64_t)h1 << 16) | ((uint64_t)h2 << 32) | ((uint64_t)h3 << 48);
  lo = (uint64_t)l0 | ((uint64_t)l1 << 16) | ((uint64_t)l2 << 32) | ((uint64_t)l3 << 48);
}

// ---------------- split-bf16 MFMA GEMM: Y = X @ W^T + bias ----------------
// X:[4096,1024] f32, W:[1024,1024] f32 (rows along K), Y f32. Tile 128x128, BK=64.
struct GemmBatch { const float* X[6]; const float* W[6]; const float* Bv[6]; float* Y[6]; };

__global__ __launch_bounds__(256, 2) void gemm_mfma_kernel(GemmBatch jobs) {
  const int jz = blockIdx.z;
  const float* __restrict__ X = jobs.X[jz];
  const float* __restrict__ W = jobs.W[jz];
  const float* __restrict__ bias = jobs.Bv[jz];
  float* __restrict__ Y = jobs.Y[jz];
  const int n0 = blockIdx.x * 128, m0 = blockIdx.y * 128;

  // fragment-packed LDS: idx16 = (c*8 + t)*64 + p  (c: K32 chunk, t: 16-row subtile,
  // p = slot permutation making both ds_read_b128 and ds_write_b64 conflict-free)
  __shared__ short Ahi[8192], Alo[8192], Bhi[8192], Blo[8192];

  const int tid = (int)threadIdx.x;
  const int q = tid >> 4, kq = tid & 15;          // staging: row-in-16, k-quad
  const int c_st = kq >> 3, m2 = (kq >> 1) & 3, half = kq & 1;
  const int p_st = (q + 16 * m2) ^ m2 ^ (c_st << 2);
  const int stBase = c_st * 4096 + p_st * 8 + half * 4;   // + rr*512

  const int l = tid & 63, wid = tid >> 6;
  const int wm = wid >> 1, wn = wid & 1;

  floatx4 acc[4][4];
#pragma unroll
  for (int i = 0; i < 4; ++i)
#pragma unroll
    for (int j = 0; j < 4; ++j) acc[i][j] = (floatx4){0.f, 0.f, 0.f, 0.f};

  const float* xrow = X + (size_t)(m0 + q) * Dsz + kq * 4;
  const float* wrow = W + (size_t)(n0 + q) * Dsz + kq * 4;

  for (int k0 = 0; k0 < Dsz; k0 += 64) {
    __syncthreads();
#pragma unroll
    for (int rr = 0; rr < 8; ++rr) {
      float4 xa = *(const float4*)(xrow + (size_t)rr * 16 * Dsz + k0);
      float4 wb = *(const float4*)(wrow + (size_t)rr * 16 * Dsz + k0);
      uint64_t ah, al, bh, bl;
      cvt_split(xa, ah, al);
      cvt_split(wb, bh, bl);
      const int off = stBase + rr * 512;
      *(uint64_t*)&Ahi[off] = ah; *(uint64_t*)&Alo[off] = al;
      *(uint64_t*)&Bhi[off] = bh; *(uint64_t*)&Blo[off] = bl;
    }
    __syncthreads();
#pragma unroll
    for (int c = 0; c < 2; ++c) {
      const int pr = (l ^ (l >> 4) ^ (c << 2)) & 63;
      short8v aH[4], aL[4], bH[4], bL[4];
#pragma unroll
      for (int t = 0; t < 4; ++t) {
        const int ia = ((c * 8 + wm * 4 + t) * 64 + pr) * 8;
        aH[t] = *(short8v*)&Ahi[ia]; aL[t] = *(short8v*)&Alo[ia];
        const int ib = ((c * 8 + wn * 4 + t) * 64 + pr) * 8;
        bH[t] = *(short8v*)&Bhi[ib]; bL[t] = *(short8v*)&Blo[ib];
      }
#pragma unroll
      for (int mt = 0; mt < 4; ++mt)
#pragma unroll
        for (int nt = 0; nt < 4; ++nt) {
          acc[mt][nt] = __builtin_amdgcn_mfma_f32_16x16x32_bf16(aH[mt], bH[nt], acc[mt][nt], 0, 0, 0);
          acc[mt][nt] = __builtin_amdgcn_mfma_f32_16x16x32_bf16(aH[mt], bL[nt], acc[mt][nt], 0, 0, 0);
          acc[mt][nt] = __builtin_amdgcn_mfma_f32_16x16x32_bf16(aL[mt], bH[nt], acc[mt][nt], 0, 0, 0);
        }
    }
  }
  // epilogue: C/D layout col=lane&15, row=(lane>>4)*4+reg  [m89-verified]
  const int colLane = l & 15, rquad = l >> 4;
#pragma unroll
  for (int nt = 0; nt < 4; ++nt) {
    const int col = n0 + wn * 64 + nt * 16 + colLane;
    const float bv = bias[col];
#pragma unroll
    for (int mt = 0; mt < 4; ++mt) {
      const int r0 = m0 + wm * 64 + mt * 16 + rquad * 4;
#pragma unroll
      for (int j = 0; j < 4; ++j)
        Y[(size_t)(r0 + j) * Dsz + col] = acc[mt][nt][j] + bv;
    }
  }
}

// ---------------- noise + diag(ent) scaling, in place on q/k/v ----------------
__global__ __launch_bounds__(256) void noise_kernel(
    float* __restrict__ qr, float* __restrict__ qi,
    float* __restrict__ kr, float* __restrict__ ki,
    float* __restrict__ vr, float* __restrict__ vi,
    const float* __restrict__ ent, AllKeys keys) {
  const uint32_t e = blockIdx.x * 256u + threadIdx.x;
  const int j = (int)blockIdx.y;
  float* re; float* im;
  if (j == 0) { re = qr; im = qi; } else if (j == 1) { re = kr; im = ki; }
  else { re = vr; im = vi; }
  const KeySet& ks = keys.t[j];
  const uint32_t b_phase = draw_bits(ks.k[0][0], ks.k[0][1], e);
  const uint32_t b_amp   = draw_bits(ks.k[1][0], ks.k[1][1], e);
  const uint32_t b_nr    = draw_bits(ks.k[2][0], ks.k[2][1], e);
  const uint32_t b_ni    = draw_bits(ks.k[3][0], ks.k[3][1], e);
  const uint32_t b_meas  = draw_bits(ks.k[4][0], ks.k[4][1], e);
  const float flip = (unif01(b_phase) < P_NOISE) ? -1.0f : 1.0f;
  const float amp  = (unif01(b_amp)  < P_NOISE) ? 1.0f : 0.0f;
  const float keep = (unif01(b_meas) < P_NOISE * 0.5f) ? 0.0f : 1.0f;
  const float nr = normal_from_bits(b_nr);
  const float ni = normal_from_bits(b_ni);
  float r  = re[e], iv = im[e];
  r  = (r  * flip + nr * S_NOISE * amp) * keep;
  iv = (iv * flip + ni * S_NOISE * amp) * keep;
  if (j != 2) {
    const int h = ((int)e & (Dsz - 1)) >> 6;
    const float d = ent[h * Hn + h];
    r *= d; iv *= d;
  }
  re[e] = r; im[e] = iv;
}

// ---------------- scores: raw S[b,h,q,k] = SCALE*(qr.kr + qi.ki), masked ------
__global__ __launch_bounds__(256) void scores_kernel(
    const float* __restrict__ qr, const float* __restrict__ qi,
    const float* __restrict__ kr, const float* __restrict__ ki,
    const int* __restrict__ mask, float* __restrict__ attn) {
  const int bh = (int)blockIdx.z;
  const int b = bh >> 4, h = bh & 15;
  const size_t base = (size_t)b * Lsz * Dsz + (size_t)h * HDsz;
  const int k0c = blockIdx.x * 64, q0 = blockIdx.y * 64;
  __shared__ float Qs[16][68];
  __shared__ float Ks[16][68];
  const int tid = (int)threadIdx.x;
  const int tx = tid & 15, ty = tid >> 4;
  const int lrow = tid >> 2, lc4 = (tid & 3) * 4;
  float acc[4][4] = {};
  for (int c = 0; c < 8; ++c) {
    const float* Qb = (c < 4) ? qr : qi;
    const float* Kb = (c < 4) ? kr : ki;
    const int d0 = (c & 3) * 16;
    float4 xv = *(const float4*)&Qb[base + (size_t)(q0 + lrow) * Dsz + d0 + lc4];
    float4 wv = *(const float4*)&Kb[base + (size_t)(k0c + lrow) * Dsz + d0 + lc4];
    __syncthreads();
    Qs[lc4 + 0][lrow] = xv.x; Qs[lc4 + 1][lrow] = xv.y;
    Qs[lc4 + 2][lrow] = xv.z; Qs[lc4 + 3][lrow] = xv.w;
    Ks[lc4 + 0][lrow] = wv.x; Ks[lc4 + 1][lrow] = wv.y;
    Ks[lc4 + 2][lrow] = wv.z; Ks[lc4 + 3][lrow] = wv.w;
    __syncthreads();
#pragma unroll
    for (int kk = 0; kk < 16; ++kk) {
      float a[4], bb[4];
#pragma unroll
      for (int i = 0; i < 4; ++i) a[i] = Qs[kk][ty * 4 + i];
#pragma unroll
      for (int j = 0; j < 4; ++j) bb[j] = Ks[kk][tx * 4 + j];
#pragma unroll
      for (int i = 0; i < 4; ++i)
#pragma unroll
        for (int j = 0; j < 4; ++j) acc[i][j] = fmaf(a[i], bb[j], acc[i][j]);
    }
  }
  const int kc = k0c + tx * 4;
  int mk[4];
#pragma unroll
  for (int j = 0; j < 4; ++j) mk[j] = mask[b * Lsz + kc + j];
#pragma unroll
  for (int i = 0; i < 4; ++i) {
    float4 o;
    o.x = (mk[0] == 0) ? -1e9f : acc[i][0] * SCALE;
    o.y = (mk[1] == 0) ? -1e9f : acc[i][1] * SCALE;
    o.z = (mk[2] == 0) ? -1e9f : acc[i][2] * SCALE;
    o.w = (mk[3] == 0) ? -1e9f : acc[i][3] * SCALE;
    *(float4*)&attn[((size_t)bh * Lsz + (q0 + ty * 4 + i)) * Lsz + kc] = o;
  }
}

// ---------------- softmax in place over last dim ----------------
__global__ __launch_bounds__(256) void softmax_kernel(float* __restrict__ attn) {
  const size_t row = blockIdx.x;
  float* p = attn + row * (size_t)Lsz;
  const int t = (int)threadIdx.x;
  float4 v = ((float4*)p)[t];
  float m = fmaxf(fmaxf(v.x, v.y), fmaxf(v.z, v.w));
  __shared__ float red[4];
  const int lane = t & 63, wv = t >> 6;
#pragma unroll
  for (int off = 32; off; off >>= 1) m = fmaxf(m, __shfl_down(m, off));
  if (lane == 0) red[wv] = m;
  __syncthreads();
  m = fmaxf(fmaxf(red[0], red[1]), fmaxf(red[2], red[3]));
  float e0 = expf(v.x - m), e1 = expf(v.y - m), e2 = expf(v.z - m), e3 = expf(v.w - m);
  float s = (e0 + e1) + (e2 + e3);
  __syncthreads();
#pragma unroll
  for (int off = 32; off; off >>= 1) s += __shfl_down(s, off);
  if (lane == 0) red[wv] = s;
  __syncthreads();
  s = (red[0] + red[1]) + (red[2] + red[3]);
  ((float4*)p)[t] = make_float4(e0 / s, e1 / s, e2 / s, e3 / s);
}

// ---------------- PV ----------------
__global__ __launch_bounds__(256) void pv_kernel(
    const float* __restrict__ attn, const float* __restrict__ vr,
    const float* __restrict__ vi, float* __restrict__ or_, float* __restrict__ oi_) {
  const int bh = (int)blockIdx.y;
  const int b = bh >> 4, h = bh & 15;
  const int q0 = blockIdx.x * 64;
  const float* arow = attn + (size_t)bh * Lsz * Lsz;
  const size_t vbase = (size_t)b * Lsz * Dsz + (size_t)h * HDsz;
  __shared__ float As[32][68];
  __shared__ float Vr[32][68];
  __shared__ float Vi[32][68];
  const int tid = (int)threadIdx.x;
  const int tx = tid & 15, ty = tid >> 4;
  const int r1 = tid >> 2, c1 = (tid & 3) * 4;
  const int r2 = tid >> 3, c2 = (tid & 7) * 8;
  float ar[4][4] = {}, ai[4][4] = {};
  for (int k0 = 0; k0 < Lsz; k0 += 32) {
    float4 a0 = *(const float4*)&arow[(size_t)(q0 + r1) * Lsz + k0 + c1];
    float4 a1 = *(const float4*)&arow[(size_t)(q0 + r1) * Lsz + k0 + 16 + c1];
    float4 v0 = *(const float4*)&vr[vbase + (size_t)(k0 + r2) * Dsz + c2];
    float4 v1 = *(const float4*)&vr[vbase + (size_t)(k0 + r2) * Dsz + c2 + 4];
    float4 w0 = *(const float4*)&vi[vbase + (size_t)(k0 + r2) * Dsz + c2];
    float4 w1 = *(const float4*)&vi[vbase + (size_t)(k0 + r2) * Dsz + c2 + 4];
    __syncthreads();
    As[c1 + 0][r1] = a0.x; As[c1 + 1][r1] = a0.y;
    As[c1 + 2][r1] = a0.z; As[c1 + 3][r1] = a0.w;
    As[16 + c1 + 0][r1] = a1.x; As[16 + c1 + 1][r1] = a1.y;
    As[16 + c1 + 2][r1] = a1.z; As[16 + c1 + 3][r1] = a1.w;
    *(float4*)&Vr[r2][c2] = v0; *(float4*)&Vr[r2][c2 + 4] = v1;
    *(float4*)&Vi[r2][c2] = w0; *(float4*)&Vi[r2][c2 + 4] = w1;
    __syncthreads();
#pragma unroll
    for (int kk = 0; kk < 32; ++kk) {
      float a[4], br[4], bi[4];
#pragma unroll
      for (int i = 0; i < 4; ++i) a[i] = As[kk][ty * 4 + i];
#pragma unroll
      for (int j = 0; j < 4; ++j) { br[j] = Vr[kk][tx * 4 + j]; bi[j] = Vi[kk][tx * 4 + j]; }
#pragma unroll
      for (int i = 0; i < 4; ++i)
#pragma unroll
        for (int j = 0; j < 4; ++j) {
          ar[i][j] = fmaf(a[i], br[j], ar[i][j]);
          ai[i][j] = fmaf(a[i], bi[j], ai[i][j]);
        }
    }
  }
#pragma unroll
  for (int i = 0; i < 4; ++i) {
    const size_t orow = (size_t)(b * Lsz + q0 + ty * 4 + i) * Dsz + h * HDsz + tx * 4;
    *(float4*)&or_[orow] = make_float4(ar[i][0], ar[i][1], ar[i][2], ar[i][3]);
    *(float4*)&oi_[orow] = make_float4(ai[i][0], ai[i][1], ai[i][2], ai[i][3]);
  }
}

extern "C" void kernel_launch(void* const* d_in, const int* in_sizes, int n_in,
                              void* d_out, int out_size, void* d_ws, size_t ws_size,
                              hipStream_t stream) {
  const float* x_real = (const float*)d_in[0];
  const float* x_imag = (const float*)d_in[1];
  const int*   mask   = (const int*)d_in[2];
  const float* qr_w = (const float*)d_in[3];  const float* qr_b = (const float*)d_in[4];
  const float* qi_w = (const float*)d_in[5];  const float* qi_b = (const float*)d_in[6];
  const float* kr_w = (const float*)d_in[7];  const float* kr_b = (const float*)d_in[8];
  const float* ki_w = (const float*)d_in[9];  const float* ki_b = (const float*)d_in[10];
  const float* vr_w = (const float*)d_in[11]; const float* vr_b = (const float*)d_in[12];
  const float* vi_w = (const float*)d_in[13]; const float* vi_b = (const float*)d_in[14];
  const float* or_w = (const float*)d_in[15]; const float* or_b = (const float*)d_in[16];
  const float* oi_w = (const float*)d_in[17]; const float* oi_b = (const float*)d_in[18];
  const float* ent  = (const float*)d_in[19];

  float* out_real = (float*)d_out;
  float* out_imag = out_real + ELEMS;
  float* attn     = out_imag + ELEMS;

  if (ws_size < 6 * ELEMS * sizeof(float)) return;
  float* ws = (float*)d_ws;
  float* qr = ws + 0 * ELEMS; float* qi = ws + 1 * ELEMS;
  float* kr = ws + 2 * ELEMS; float* ki = ws + 3 * ELEMS;
  float* vr = ws + 4 * ELEMS; float* vi = ws + 5 * ELEMS;
  float* or_tmp = qr;
  float* oi_tmp = qi;

  AllKeys keys;
  for (int j = 0; j < 3; ++j) {
    uint32_t a, b2;
    tf2x32(0u, 1u, 0u, (uint32_t)j, a, b2);
#if PARTITIONABLE
    for (int i = 0; i < 5; ++i)
      tf2x32(a, b2, 0u, (uint32_t)i, keys.t[j].k[i][0], keys.t[j].k[i][1]);
#else
    uint32_t out10[10];
    for (int i = 0; i < 5; ++i) {
      uint32_t o0, o1; tf2x32(a, b2, (uint32_t)i, (uint32_t)(i + 5), o0, o1);
      out10[i] = o0; out10[i + 5] = o1;
    }
    for (int i = 0; i < 5; ++i) { keys.t[j].k[i][0] = out10[2*i]; keys.t[j].k[i][1] = out10[2*i+1]; }
#endif
  }

  // 1) six projection GEMMs (split-bf16 MFMA)
  GemmBatch pj;
  const float* xs[6] = {x_real, x_imag, x_real, x_imag, x_real, x_imag};
  const float* wsp[6] = {qr_w, qi_w, kr_w, ki_w, vr_w, vi_w};
  const float* bsp[6] = {qr_b, qi_b, kr_b, ki_b, vr_b, vi_b};
  float* ysp[6] = {qr, qi, kr, ki, vr, vi};
  for (int i = 0; i < 6; ++i) { pj.X[i] = xs[i]; pj.W[i] = wsp[i]; pj.Bv[i] = bsp[i]; pj.Y[i] = ysp[i]; }
  gemm_mfma_kernel<<<dim3(8, 32, 6), 256, 0, stream>>>(pj);

  // 2) quantum noise + diag(ent)
  noise_kernel<<<dim3((uint32_t)(ELEMS / 256), 3), 256, 0, stream>>>(qr, qi, kr, ki, vr, vi, ent, keys);

  // 3) raw interference scores
  scores_kernel<<<dim3(16, 16, 64), 256, 0, stream>>>(qr, qi, kr, ki, mask, attn);

  // 4) softmax in place
  softmax_kernel<<<dim3(Bsz * Hn * Lsz), 256, 0, stream>>>(attn);

  // 5) PV
  pv_kernel<<<dim3(16, 64), 256, 0, stream>>>(attn, vr, vi, or_tmp, oi_tmp);

  // 6) output projections (split-bf16 MFMA)
  GemmBatch oj;
  for (int i = 0; i < 6; ++i) { oj.X[i] = nullptr; oj.W[i] = nullptr; oj.Bv[i] = nullptr; oj.Y[i] = nullptr; }
  oj.X[0] = or_tmp; oj.W[0] = or_w; oj.Bv[0] = or_b; oj.Y[0] = out_real;
  oj.X[1] = oi_tmp; oj.W[1] = oi_w; oj.Bv[1] = oi_b; oj.Y[1] = out_imag;
  gemm_mfma_kernel<<<dim3(8, 32, 2), 256, 0, stream>>>(oj);
}

// Round 3
// 752.755 us; speedup vs baseline: 2.1721x; 1.3499x over previous
//
#include <hip/hip_runtime.h>
#include <cstdint>

#define PARTITIONABLE 1

static constexpr int Bsz = 4, Lsz = 1024, Dsz = 1024, Hn = 16, HDsz = 64;
static constexpr size_t ELEMS = (size_t)Bsz * Lsz * Dsz;     // 4194304
static constexpr uint32_t HALF_N = (uint32_t)(ELEMS / 2);
static constexpr float SCALE = 0.125f;
static constexpr float P_NOISE = 0.05f;
static constexpr float S_NOISE = 0.1f;

typedef __attribute__((ext_vector_type(8))) short short8v;   // 8 bf16 (4 VGPR)
typedef __attribute__((ext_vector_type(4))) float floatx4;   // MFMA acc
typedef __attribute__((ext_vector_type(4))) unsigned int uint4v;

// ---------------- threefry2x32 (exact JAX semantics) ----------------
__host__ __device__ __forceinline__ void tf2x32(uint32_t k0, uint32_t k1,
                                                uint32_t x0, uint32_t x1,
                                                uint32_t& o0, uint32_t& o1) {
  uint32_t ks2 = k0 ^ k1 ^ 0x1BD11BDAu;
  x0 += k0; x1 += k1;
#define TFR(r) { x0 += x1; x1 = (x1 << (r)) | (x1 >> (32 - (r))); x1 ^= x0; }
  TFR(13) TFR(15) TFR(26) TFR(6)
  x0 += k1; x1 += ks2 + 1u;
  TFR(17) TFR(29) TFR(16) TFR(24)
  x0 += ks2; x1 += k0 + 2u;
  TFR(13) TFR(15) TFR(26) TFR(6)
  x0 += k0; x1 += k1 + 3u;
  TFR(17) TFR(29) TFR(16) TFR(24)
  x0 += k1; x1 += ks2 + 4u;
  TFR(13) TFR(15) TFR(26) TFR(6)
  x0 += ks2; x1 += k0 + 5u;
#undef TFR
  o0 = x0; o1 = x1;
}

struct KeySet { uint32_t k[5][2]; };
struct AllKeys { KeySet t[3]; };

__device__ __forceinline__ uint32_t draw_bits(uint32_t k0, uint32_t k1, uint32_t idx) {
#if PARTITIONABLE
  uint32_t o0, o1; tf2x32(k0, k1, 0u, idx, o0, o1);
  return o0 ^ o1;
#else
  uint32_t o0, o1;
  if (idx < HALF_N) { tf2x32(k0, k1, idx, idx + HALF_N, o0, o1); return o0; }
  tf2x32(k0, k1, idx - HALF_N, idx, o0, o1); return o1;
#endif
}

__device__ __forceinline__ float unif01(uint32_t bits) {
  return __uint_as_float((bits >> 9) | 0x3f800000u) - 1.0f;
}

__device__ __forceinline__ float normal_from_bits(uint32_t bits) {
  const float LO = -0.99999994f;
  float f = unif01(bits);
  float x = fmaxf(LO, f * 2.0f + LO);
  float w = -log1pf(-x * x);
  float p;
  if (w < 5.0f) {
    w = w - 2.5f;
    p = 2.81022636e-08f;
    p = fmaf(p, w, 3.43273939e-07f);
    p = fmaf(p, w, -3.5233877e-06f);
    p = fmaf(p, w, -4.39150654e-06f);
    p = fmaf(p, w, 0.00021858087f);
    p = fmaf(p, w, -0.00125372503f);
    p = fmaf(p, w, -0.00417768164f);
    p = fmaf(p, w, 0.246640727f);
    p = fmaf(p, w, 1.50140941f);
  } else {
    w = sqrtf(w) - 3.0f;
    p = -0.000200214257f;
    p = fmaf(p, w, 0.000100950558f);
    p = fmaf(p, w, 0.00134934322f);
    p = fmaf(p, w, -0.00367342844f);
    p = fmaf(p, w, 0.00573950773f);
    p = fmaf(p, w, -0.0076224613f);
    p = fmaf(p, w, 0.00943887047f);
    p = fmaf(p, w, 1.00167406f);
    p = fmaf(p, w, 2.83297682f);
  }
  return 1.41421356f * (p * x);
}

// ---------------- f32 -> (hi,lo) bf16 split ----------------
__device__ __forceinline__ uint32_t bf16_rn(float f) {
  uint32_t u = __float_as_uint(f);
  return (u + 0x7FFFu + ((u >> 16) & 1u)) >> 16;
}
__device__ __forceinline__ void cvt_split(float4 v, uint64_t& hi, uint64_t& lo) {
  uint32_t h0 = bf16_rn(v.x), h1 = bf16_rn(v.y), h2 = bf16_rn(v.z), h3 = bf16_rn(v.w);
  float r0 = v.x - __uint_as_float(h0 << 16);
  float r1 = v.y - __uint_as_float(h1 << 16);
  float r2 = v.z - __uint_as_float(h2 << 16);
  float r3 = v.w - __uint_as_float(h3 << 16);
  uint32_t l0 = bf16_rn(r0), l1 = bf16_rn(r1), l2 = bf16_rn(r2), l3 = bf16_rn(r3);
  hi = (uint64_t)h0 | ((uint64_t)h1 << 16) | ((uint64_t)h2 << 32) | ((uint64_t)h3 << 48);
  lo = (uint64_t)l0 | ((uint64_t)l1 << 16) | ((uint64_t)l2 << 32) | ((uint64_t)l3 << 48);
}

// ---------------- split-bf16 MFMA GEMM: Y = X @ W^T + bias ----------------
struct GemmBatch { const float* X[6]; const float* W[6]; const float* Bv[6]; float* Y[6]; };

__global__ __launch_bounds__(256, 2) void gemm_mfma_kernel(GemmBatch jobs) {
  const int jz = blockIdx.z;
  const float* __restrict__ X = jobs.X[jz];
  const float* __restrict__ W = jobs.W[jz];
  const float* __restrict__ bias = jobs.Bv[jz];
  float* __restrict__ Y = jobs.Y[jz];
  const int n0 = blockIdx.x * 128, m0 = blockIdx.y * 128;

  __shared__ short Ahi[8192], Alo[8192], Bhi[8192], Blo[8192];

  const int tid = (int)threadIdx.x;
  const int q = tid >> 4, kq = tid & 15;
  const int c_st = kq >> 3, m2 = (kq >> 1) & 3, half = kq & 1;
  const int p_st = (q + 16 * m2) ^ m2 ^ (c_st << 2);
  const int stBase = c_st * 4096 + p_st * 8 + half * 4;

  const int l = tid & 63, wid = tid >> 6;
  const int wm = wid >> 1, wn = wid & 1;

  floatx4 acc[4][4];
#pragma unroll
  for (int i = 0; i < 4; ++i)
#pragma unroll
    for (int j = 0; j < 4; ++j) acc[i][j] = (floatx4){0.f, 0.f, 0.f, 0.f};

  const float* xrow = X + (size_t)(m0 + q) * Dsz + kq * 4;
  const float* wrow = W + (size_t)(n0 + q) * Dsz + kq * 4;

  for (int k0 = 0; k0 < Dsz; k0 += 64) {
    __syncthreads();
#pragma unroll
    for (int rr = 0; rr < 8; ++rr) {
      float4 xa = *(const float4*)(xrow + (size_t)rr * 16 * Dsz + k0);
      float4 wb = *(const float4*)(wrow + (size_t)rr * 16 * Dsz + k0);
      uint64_t ah, al, bh, bl;
      cvt_split(xa, ah, al);
      cvt_split(wb, bh, bl);
      const int off = stBase + rr * 512;
      *(uint64_t*)&Ahi[off] = ah; *(uint64_t*)&Alo[off] = al;
      *(uint64_t*)&Bhi[off] = bh; *(uint64_t*)&Blo[off] = bl;
    }
    __syncthreads();
#pragma unroll
    for (int c = 0; c < 2; ++c) {
      const int pr = (l ^ (l >> 4) ^ (c << 2)) & 63;
      short8v aH[4], aL[4], bH[4], bL[4];
#pragma unroll
      for (int t = 0; t < 4; ++t) {
        const int ia = ((c * 8 + wm * 4 + t) * 64 + pr) * 8;
        aH[t] = *(short8v*)&Ahi[ia]; aL[t] = *(short8v*)&Alo[ia];
        const int ib = ((c * 8 + wn * 4 + t) * 64 + pr) * 8;
        bH[t] = *(short8v*)&Bhi[ib]; bL[t] = *(short8v*)&Blo[ib];
      }
#pragma unroll
      for (int mt = 0; mt < 4; ++mt)
#pragma unroll
        for (int nt = 0; nt < 4; ++nt) {
          acc[mt][nt] = __builtin_amdgcn_mfma_f32_16x16x32_bf16(aH[mt], bH[nt], acc[mt][nt], 0, 0, 0);
          acc[mt][nt] = __builtin_amdgcn_mfma_f32_16x16x32_bf16(aH[mt], bL[nt], acc[mt][nt], 0, 0, 0);
          acc[mt][nt] = __builtin_amdgcn_mfma_f32_16x16x32_bf16(aL[mt], bH[nt], acc[mt][nt], 0, 0, 0);
        }
    }
  }
  const int colLane = l & 15, rquad = l >> 4;
#pragma unroll
  for (int nt = 0; nt < 4; ++nt) {
    const int col = n0 + wn * 64 + nt * 16 + colLane;
    const float bv = bias[col];
#pragma unroll
    for (int mt = 0; mt < 4; ++mt) {
      const int r0 = m0 + wm * 64 + mt * 16 + rquad * 4;
#pragma unroll
      for (int j = 0; j < 4; ++j)
        Y[(size_t)(r0 + j) * Dsz + col] = acc[mt][nt][j] + bv;
    }
  }
}

// ---------------- scores MFMA: S[bh,q,k] = SCALE*(qr.kr + qi.ki), masked ------
__global__ __launch_bounds__(256, 2) void scores_mfma_kernel(
    const float* __restrict__ qr, const float* __restrict__ qi,
    const float* __restrict__ kr, const float* __restrict__ ki,
    const int* __restrict__ mask, float* __restrict__ attn) {
  const int bh = (int)blockIdx.z;
  const int b = bh >> 4, h = bh & 15;
  const int n0 = blockIdx.x * 128, m0 = blockIdx.y * 128;

  __shared__ short Ahi[8192], Alo[8192], Bhi[8192], Blo[8192];

  const int tid = (int)threadIdx.x;
  const int q = tid >> 4, kq = tid & 15;
  const int c_st = kq >> 3, m2 = (kq >> 1) & 3, half = kq & 1;
  const int p_st = (q + 16 * m2) ^ m2 ^ (c_st << 2);
  const int stBase = c_st * 4096 + p_st * 8 + half * 4;

  const int l = tid & 63, wid = tid >> 6;
  const int wm = wid >> 1, wn = wid & 1;

  floatx4 acc[4][4];
#pragma unroll
  for (int i = 0; i < 4; ++i)
#pragma unroll
    for (int j = 0; j < 4; ++j) acc[i][j] = (floatx4){0.f, 0.f, 0.f, 0.f};

  const size_t qbase = ((size_t)(b * Lsz) + m0 + q) * Dsz + h * HDsz + kq * 4;
  const size_t kbase = ((size_t)(b * Lsz) + n0 + q) * Dsz + h * HDsz + kq * 4;

#pragma unroll
  for (int k0 = 0; k0 < 128; k0 += 64) {
    const float* Xb = k0 ? qi : qr;
    const float* Wb = k0 ? ki : kr;
    __syncthreads();
#pragma unroll
    for (int rr = 0; rr < 8; ++rr) {
      float4 xa = *(const float4*)(Xb + qbase + (size_t)rr * 16 * Dsz);
      float4 wb = *(const float4*)(Wb + kbase + (size_t)rr * 16 * Dsz);
      uint64_t ah, al, bhv, blv;
      cvt_split(xa, ah, al);
      cvt_split(wb, bhv, blv);
      const int off = stBase + rr * 512;
      *(uint64_t*)&Ahi[off] = ah; *(uint64_t*)&Alo[off] = al;
      *(uint64_t*)&Bhi[off] = bhv; *(uint64_t*)&Blo[off] = blv;
    }
    __syncthreads();
#pragma unroll
    for (int c = 0; c < 2; ++c) {
      const int pr = (l ^ (l >> 4) ^ (c << 2)) & 63;
      short8v aH[4], aL[4], bH[4], bL[4];
#pragma unroll
      for (int t = 0; t < 4; ++t) {
        const int ia = ((c * 8 + wm * 4 + t) * 64 + pr) * 8;
        aH[t] = *(short8v*)&Ahi[ia]; aL[t] = *(short8v*)&Alo[ia];
        const int ib = ((c * 8 + wn * 4 + t) * 64 + pr) * 8;
        bH[t] = *(short8v*)&Bhi[ib]; bL[t] = *(short8v*)&Blo[ib];
      }
#pragma unroll
      for (int mt = 0; mt < 4; ++mt)
#pragma unroll
        for (int nt = 0; nt < 4; ++nt) {
          acc[mt][nt] = __builtin_amdgcn_mfma_f32_16x16x32_bf16(aH[mt], bH[nt], acc[mt][nt], 0, 0, 0);
          acc[mt][nt] = __builtin_amdgcn_mfma_f32_16x16x32_bf16(aH[mt], bL[nt], acc[mt][nt], 0, 0, 0);
          acc[mt][nt] = __builtin_amdgcn_mfma_f32_16x16x32_bf16(aL[mt], bH[nt], acc[mt][nt], 0, 0, 0);
        }
    }
  }
  const int colLane = l & 15, rquad = l >> 4;
#pragma unroll
  for (int nt = 0; nt < 4; ++nt) {
    const int col = n0 + wn * 64 + nt * 16 + colLane;
    const int mv = mask[b * Lsz + col];
#pragma unroll
    for (int mt = 0; mt < 4; ++mt) {
      const int r0 = m0 + wm * 64 + mt * 16 + rquad * 4;
#pragma unroll
      for (int j = 0; j < 4; ++j)
        attn[((size_t)bh * Lsz + r0 + j) * Lsz + col] =
            (mv == 0) ? -1e9f : acc[mt][nt][j] * SCALE;
    }
  }
}

// ---------------- V transpose: vr/vi f32 [b][k][d] -> Vt hi/lo bf16 [bh][n][k] --
__global__ __launch_bounds__(256) void vtrans_kernel(
    const float* __restrict__ vr, const float* __restrict__ vi,
    unsigned short* __restrict__ vth, unsigned short* __restrict__ vtl) {
  const int bh = (int)blockIdx.y;
  const int b = bh >> 4, h = bh & 15;
  const int k0 = blockIdx.x * 64;
  __shared__ uint32_t T[128 * 65];    // [n][klocal], lo | hi<<16
  const int t = (int)threadIdx.x;
  const int krow = t >> 4, d4 = (t & 15) * 4;

#pragma unroll
  for (int src = 0; src < 2; ++src) {
    const float* V = src ? vi : vr;
    const int nb = src * 64;
#pragma unroll
    for (int p = 0; p < 4; ++p) {
      const int k = p * 16 + krow;
      float4 v = *(const float4*)&V[((size_t)(b * Lsz) + k0 + k) * Dsz + h * HDsz + d4];
      float fv[4] = {v.x, v.y, v.z, v.w};
#pragma unroll
      for (int e = 0; e < 4; ++e) {
        uint32_t hi = bf16_rn(fv[e]);
        float r = fv[e] - __uint_as_float(hi << 16);
        uint32_t lo = bf16_rn(r);
        T[(nb + d4 + e) * 65 + k] = lo | (hi << 16);
      }
    }
  }
  __syncthreads();
  const int n = t >> 1, hf = t & 1;
  const size_t rowb = ((size_t)bh * 128 + n) * Lsz + k0 + hf * 32;
#pragma unroll
  for (int g = 0; g < 4; ++g) {
    uint32_t w[8];
#pragma unroll
    for (int u = 0; u < 8; ++u) w[u] = T[n * 65 + hf * 32 + g * 8 + u];
    uint4v hv, lv;
    hv.x = (w[0] >> 16) | (w[1] & 0xFFFF0000u);
    hv.y = (w[2] >> 16) | (w[3] & 0xFFFF0000u);
    hv.z = (w[4] >> 16) | (w[5] & 0xFFFF0000u);
    hv.w = (w[6] >> 16) | (w[7] & 0xFFFF0000u);
    lv.x = (w[0] & 0xFFFFu) | (w[1] << 16);
    lv.y = (w[2] & 0xFFFFu) | (w[3] << 16);
    lv.z = (w[4] & 0xFFFFu) | (w[5] << 16);
    lv.w = (w[6] & 0xFFFFu) | (w[7] << 16);
    *(uint4v*)&vth[rowb + g * 8] = hv;
    *(uint4v*)&vtl[rowb + g * 8] = lv;
  }
}

// ---------------- PV MFMA: O[bh,q,n] = sum_k attn[bh,q,k] * Vt[bh,n,k] --------
__global__ __launch_bounds__(256, 2) void pv_mfma_kernel(
    const float* __restrict__ attn,
    const unsigned short* __restrict__ vth, const unsigned short* __restrict__ vtl,
    float* __restrict__ or_, float* __restrict__ oi_) {
  const int bh = (int)blockIdx.y;
  const int b = bh >> 4, h = bh & 15;
  const int m0 = blockIdx.x * 128;

  __shared__ short Ahi[8192], Alo[8192], Bhi[8192], Blo[8192];

  const int tid = (int)threadIdx.x;
  const int q = tid >> 4, kq = tid & 15;
  const int c_st = kq >> 3, m2 = (kq >> 1) & 3, half = kq & 1;
  const int p_st = (q + 16 * m2) ^ m2 ^ (c_st << 2);
  const int stBase = c_st * 4096 + p_st * 8 + half * 4;

  const int l = tid & 63, wid = tid >> 6;
  const int wm = wid >> 1, wn = wid & 1;

  floatx4 acc[4][4];
#pragma unroll
  for (int i = 0; i < 4; ++i)
#pragma unroll
    for (int j = 0; j < 4; ++j) acc[i][j] = (floatx4){0.f, 0.f, 0.f, 0.f};

  const float* arow = attn + ((size_t)bh * Lsz + m0 + q) * Lsz + kq * 4;
  const unsigned short* bhrow = vth + ((size_t)bh * 128 + q) * Lsz + kq * 4;
  const unsigned short* blrow = vtl + ((size_t)bh * 128 + q) * Lsz + kq * 4;

  for (int k0 = 0; k0 < Lsz; k0 += 64) {
    __syncthreads();
#pragma unroll
    for (int rr = 0; rr < 8; ++rr) {
      float4 av = *(const float4*)(arow + (size_t)rr * 16 * Lsz + k0);
      uint64_t ah, al;
      cvt_split(av, ah, al);
      uint64_t bhv = *(const uint64_t*)(bhrow + (size_t)rr * 16 * Lsz + k0);
      uint64_t blv = *(const uint64_t*)(blrow + (size_t)rr * 16 * Lsz + k0);
      const int off = stBase + rr * 512;
      *(uint64_t*)&Ahi[off] = ah; *(uint64_t*)&Alo[off] = al;
      *(uint64_t*)&Bhi[off] = bhv; *(uint64_t*)&Blo[off] = blv;
    }
    __syncthreads();
#pragma unroll
    for (int c = 0; c < 2; ++c) {
      const int pr = (l ^ (l >> 4) ^ (c << 2)) & 63;
      short8v aH[4], aL[4], bH[4], bL[4];
#pragma unroll
      for (int t = 0; t < 4; ++t) {
        const int ia = ((c * 8 + wm * 4 + t) * 64 + pr) * 8;
        aH[t] = *(short8v*)&Ahi[ia]; aL[t] = *(short8v*)&Alo[ia];
        const int ib = ((c * 8 + wn * 4 + t) * 64 + pr) * 8;
        bH[t] = *(short8v*)&Bhi[ib]; bL[t] = *(short8v*)&Blo[ib];
      }
#pragma unroll
      for (int mt = 0; mt < 4; ++mt)
#pragma unroll
        for (int nt = 0; nt < 4; ++nt) {
          acc[mt][nt] = __builtin_amdgcn_mfma_f32_16x16x32_bf16(aH[mt], bH[nt], acc[mt][nt], 0, 0, 0);
          acc[mt][nt] = __builtin_amdgcn_mfma_f32_16x16x32_bf16(aH[mt], bL[nt], acc[mt][nt], 0, 0, 0);
          acc[mt][nt] = __builtin_amdgcn_mfma_f32_16x16x32_bf16(aL[mt], bH[nt], acc[mt][nt], 0, 0, 0);
        }
    }
  }
  const int colLane = l & 15, rquad = l >> 4;
#pragma unroll
  for (int nt = 0; nt < 4; ++nt) {
    const int col = wn * 64 + nt * 16 + colLane;     // 0..127
    float* O = (col < 64) ? or_ : oi_;
    const int dcol = col & 63;
#pragma unroll
    for (int mt = 0; mt < 4; ++mt) {
      const int r0 = m0 + wm * 64 + mt * 16 + rquad * 4;
#pragma unroll
      for (int j = 0; j < 4; ++j)
        O[((size_t)(b * Lsz) + r0 + j) * Dsz + h * HDsz + dcol] = acc[mt][nt][j];
    }
  }
}

// ---------------- noise + diag(ent) scaling, in place on q/k/v ----------------
__global__ __launch_bounds__(256) void noise_kernel(
    float* __restrict__ qr, float* __restrict__ qi,
    float* __restrict__ kr, float* __restrict__ ki,
    float* __restrict__ vr, float* __restrict__ vi,
    const float* __restrict__ ent, AllKeys keys) {
  const uint32_t e = blockIdx.x * 256u + threadIdx.x;
  const int j = (int)blockIdx.y;
  float* re; float* im;
  if (j == 0) { re = qr; im = qi; } else if (j == 1) { re = kr; im = ki; }
  else { re = vr; im = vi; }
  const KeySet& ks = keys.t[j];
  const uint32_t b_phase = draw_bits(ks.k[0][0], ks.k[0][1], e);
  const uint32_t b_amp   = draw_bits(ks.k[1][0], ks.k[1][1], e);
  const uint32_t b_nr    = draw_bits(ks.k[2][0], ks.k[2][1], e);
  const uint32_t b_ni    = draw_bits(ks.k[3][0], ks.k[3][1], e);
  const uint32_t b_meas  = draw_bits(ks.k[4][0], ks.k[4][1], e);
  const float flip = (unif01(b_phase) < P_NOISE) ? -1.0f : 1.0f;
  const float amp  = (unif01(b_amp)  < P_NOISE) ? 1.0f : 0.0f;
  const float keep = (unif01(b_meas) < P_NOISE * 0.5f) ? 0.0f : 1.0f;
  const float nr = normal_from_bits(b_nr);
  const float ni = normal_from_bits(b_ni);
  float r  = re[e], iv = im[e];
  r  = (r  * flip + nr * S_NOISE * amp) * keep;
  iv = (iv * flip + ni * S_NOISE * amp) * keep;
  if (j != 2) {
    const int h = ((int)e & (Dsz - 1)) >> 6;
    const float d = ent[h * Hn + h];
    r *= d; iv *= d;
  }
  re[e] = r; im[e] = iv;
}

// ---------------- softmax in place over last dim ----------------
__global__ __launch_bounds__(256) void softmax_kernel(float* __restrict__ attn) {
  const size_t row = blockIdx.x;
  float* p = attn + row * (size_t)Lsz;
  const int t = (int)threadIdx.x;
  float4 v = ((float4*)p)[t];
  float m = fmaxf(fmaxf(v.x, v.y), fmaxf(v.z, v.w));
  __shared__ float red[4];
  const int lane = t & 63, wv = t >> 6;
#pragma unroll
  for (int off = 32; off; off >>= 1) m = fmaxf(m, __shfl_down(m, off));
  if (lane == 0) red[wv] = m;
  __syncthreads();
  m = fmaxf(fmaxf(red[0], red[1]), fmaxf(red[2], red[3]));
  float e0 = expf(v.x - m), e1 = expf(v.y - m), e2 = expf(v.z - m), e3 = expf(v.w - m);
  float s = (e0 + e1) + (e2 + e3);
  __syncthreads();
#pragma unroll
  for (int off = 32; off; off >>= 1) s += __shfl_down(s, off);
  if (lane == 0) red[wv] = s;
  __syncthreads();
  s = (red[0] + red[1]) + (red[2] + red[3]);
  ((float4*)p)[t] = make_float4(e0 / s, e1 / s, e2 / s, e3 / s);
}

extern "C" void kernel_launch(void* const* d_in, const int* in_sizes, int n_in,
                              void* d_out, int out_size, void* d_ws, size_t ws_size,
                              hipStream_t stream) {
  const float* x_real = (const float*)d_in[0];
  const float* x_imag = (const float*)d_in[1];
  const int*   mask   = (const int*)d_in[2];
  const float* qr_w = (const float*)d_in[3];  const float* qr_b = (const float*)d_in[4];
  const float* qi_w = (const float*)d_in[5];  const float* qi_b = (const float*)d_in[6];
  const float* kr_w = (const float*)d_in[7];  const float* kr_b = (const float*)d_in[8];
  const float* ki_w = (const float*)d_in[9];  const float* ki_b = (const float*)d_in[10];
  const float* vr_w = (const float*)d_in[11]; const float* vr_b = (const float*)d_in[12];
  const float* vi_w = (const float*)d_in[13]; const float* vi_b = (const float*)d_in[14];
  const float* or_w = (const float*)d_in[15]; const float* or_b = (const float*)d_in[16];
  const float* oi_w = (const float*)d_in[17]; const float* oi_b = (const float*)d_in[18];
  const float* ent  = (const float*)d_in[19];

  float* out_real = (float*)d_out;
  float* out_imag = out_real + ELEMS;
  float* attn     = out_imag + ELEMS;

  if (ws_size < 6 * ELEMS * sizeof(float)) return;
  float* ws = (float*)d_ws;
  float* qr = ws + 0 * ELEMS; float* qi = ws + 1 * ELEMS;
  float* kr = ws + 2 * ELEMS; float* ki = ws + 3 * ELEMS;
  float* vr = ws + 4 * ELEMS; float* vi = ws + 5 * ELEMS;
  float* or_tmp = qr;                            // dead after scores
  float* oi_tmp = qi;
  unsigned short* vth = (unsigned short*)kr;     // dead after scores; 64*128*1024 u16 = 16 MB
  unsigned short* vtl = (unsigned short*)ki;

  AllKeys keys;
  for (int j = 0; j < 3; ++j) {
    uint32_t a, b2;
    tf2x32(0u, 1u, 0u, (uint32_t)j, a, b2);
#if PARTITIONABLE
    for (int i = 0; i < 5; ++i)
      tf2x32(a, b2, 0u, (uint32_t)i, keys.t[j].k[i][0], keys.t[j].k[i][1]);
#else
    uint32_t out10[10];
    for (int i = 0; i < 5; ++i) {
      uint32_t o0, o1; tf2x32(a, b2, (uint32_t)i, (uint32_t)(i + 5), o0, o1);
      out10[i] = o0; out10[i + 5] = o1;
    }
    for (int i = 0; i < 5; ++i) { keys.t[j].k[i][0] = out10[2*i]; keys.t[j].k[i][1] = out10[2*i+1]; }
#endif
  }

  // 1) six projection GEMMs (split-bf16 MFMA)
  GemmBatch pj;
  const float* xs[6] = {x_real, x_imag, x_real, x_imag, x_real, x_imag};
  const float* wsp[6] = {qr_w, qi_w, kr_w, ki_w, vr_w, vi_w};
  const float* bsp[6] = {qr_b, qi_b, kr_b, ki_b, vr_b, vi_b};
  float* ysp[6] = {qr, qi, kr, ki, vr, vi};
  for (int i = 0; i < 6; ++i) { pj.X[i] = xs[i]; pj.W[i] = wsp[i]; pj.Bv[i] = bsp[i]; pj.Y[i] = ysp[i]; }
  gemm_mfma_kernel<<<dim3(8, 32, 6), 256, 0, stream>>>(pj);

  // 2) quantum noise + diag(ent)
  noise_kernel<<<dim3((uint32_t)(ELEMS / 256), 3), 256, 0, stream>>>(qr, qi, kr, ki, vr, vi, ent, keys);

  // 3) raw interference scores (MFMA)
  scores_mfma_kernel<<<dim3(8, 8, 64), 256, 0, stream>>>(qr, qi, kr, ki, mask, attn);

  // 4) V transpose into dead kr/ki (split bf16)
  vtrans_kernel<<<dim3(16, 64), 256, 0, stream>>>(vr, vi, vth, vtl);

  // 5) softmax in place
  softmax_kernel<<<dim3(Bsz * Hn * Lsz), 256, 0, stream>>>(attn);

  // 6) PV (MFMA)
  pv_mfma_kernel<<<dim3(8, 64), 256, 0, stream>>>(attn, vth, vtl, or_tmp, oi_tmp);

  // 7) output projections (split-bf16 MFMA)
  GemmBatch oj;
  for (int i = 0; i < 6; ++i) { oj.X[i] = nullptr; oj.W[i] = nullptr; oj.Bv[i] = nullptr; oj.Y[i] = nullptr; }
  oj.X[0] = or_tmp; oj.W[0] = or_w; oj.Bv[0] = or_b; oj.Y[0] = out_real;
  oj.X[1] = oi_tmp; oj.W[1] = oi_w; oj.Bv[1] = oi_b; oj.Y[1] = out_imag;
  gemm_mfma_kernel<<<dim3(8, 32, 2), 256, 0, stream>>>(oj);
}